// Round 8
// baseline (156.894 us; speedup 1.0000x reference)
//
#include <hip/hip_runtime.h>
#include <hip/hip_fp16.h>

#define IN_DIM  16384
#define OUT_DIM 16384
#define BATCH   2048
#define NBLK    512
#define RPB     (BATCH / NBLK)          // 4 rows per block
#define TPB     512
#define ITS     (OUT_DIM / (TPB * 4))   // 8 j-iterations (4 columns each)
#define CHK     (IN_DIM / (TPB * 8))    // 4 chunks of 8 floats per thread

typedef float f32x4 __attribute__((ext_vector_type(4)));

// Two half2's per output column: ab = (c0, c1), cd = (c2, c3). 8 bytes.
struct h2x2 { __half2 ab, cd; };

// OP_COEFFS from the reference, row-major [16][4]
__device__ __constant__ float OPC[16][4] = {
    {0.f, 0.f, 0.f, 0.f}, {0.f, 0.f, 0.f, 1.f}, {0.f, 1.f, 0.f, -1.f}, {0.f, 1.f, 0.f, 0.f},
    {0.f, 0.f, 1.f, -1.f}, {0.f, 0.f, 1.f, 0.f}, {0.f, 1.f, 1.f, -2.f}, {0.f, 1.f, 1.f, -1.f},
    {1.f, -1.f, -1.f, 1.f}, {1.f, -1.f, -1.f, 2.f}, {1.f, 0.f, -1.f, 0.f}, {1.f, 0.f, -1.f, 1.f},
    {1.f, -1.f, 0.f, 0.f}, {1.f, -1.f, 0.f, 1.f}, {1.f, 0.f, 0.f, -1.f}, {1.f, 0.f, 0.f, 0.f}};

// Prep: coef (f16x4) + packed f16-LDS byte offsets: (idx_a*2) | (idx_b*2)<<16.
__global__ __launch_bounds__(256) void prep_kernel(const float* __restrict__ w,
                                                   const int* __restrict__ ia,
                                                   const int* __restrict__ ib,
                                                   h2x2* __restrict__ coefh,
                                                   unsigned* __restrict__ packed) {
    int j = blockIdx.x * 256 + threadIdx.x;
    if (j >= OUT_DIM) return;

    const float4* wr = (const float4*)(w + (size_t)j * 16);
    float wv[16];
    float4 w0 = wr[0], w1 = wr[1], w2 = wr[2], w3 = wr[3];
    wv[0] = w0.x; wv[1] = w0.y; wv[2] = w0.z; wv[3] = w0.w;
    wv[4] = w1.x; wv[5] = w1.y; wv[6] = w1.z; wv[7] = w1.w;
    wv[8] = w2.x; wv[9] = w2.y; wv[10] = w2.z; wv[11] = w2.w;
    wv[12] = w3.x; wv[13] = w3.y; wv[14] = w3.z; wv[15] = w3.w;

    float m = wv[0];
#pragma unroll
    for (int k = 1; k < 16; ++k) m = fmaxf(m, wv[k]);
    float s = 0.f;
#pragma unroll
    for (int k = 0; k < 16; ++k) { wv[k] = expf(wv[k] - m); s += wv[k]; }
    float inv = 1.f / s;

    float c0 = 0.f, c1 = 0.f, c2 = 0.f, c3 = 0.f;
#pragma unroll
    for (int k = 0; k < 16; ++k) {
        float p = wv[k];
        c0 = fmaf(p, OPC[k][0], c0);
        c1 = fmaf(p, OPC[k][1], c1);
        c2 = fmaf(p, OPC[k][2], c2);
        c3 = fmaf(p, OPC[k][3], c3);
    }
    h2x2 c;
    c.ab = __floats2half2_rn(c0 * inv, c1 * inv);
    c.cd = __floats2half2_rn(c2 * inv, c3 * inv);
    coefh[j] = c;
    packed[j] = ((unsigned)ia[j] << 1) | ((unsigned)ib[j] << 17);
}

__device__ __forceinline__ unsigned pack2(float a, float b) {
    __half2 h = __floats2half2_rn(a, b);
    return *(unsigned*)&h;
}

// f16 row double-buffer (2x32KiB = 64KiB LDS) -> 2 independent blocks/CU:
// barrier drains of one block overlap the other block's compute. pk hoisted
// (address critical path); cf STREAMED from L2 per iteration (consumed by the
// final FMAs, latency hides under ds_read). Stage regs f16-packed (16 VGPRs).
// Total live ~90 < 128 cap: no spill (the R4/R5/R7 failure mode).
__global__ __launch_bounds__(TPB, 4) void logic_kernel(const float* __restrict__ x,
                                                       const unsigned* __restrict__ packed,
                                                       const h2x2* __restrict__ coefh,
                                                       float* __restrict__ out) {
    __shared__ __half lds[2][IN_DIM];  // 64 KiB total -> 2 blocks/CU

    const int tid = threadIdx.x;
    const int row0 = blockIdx.x * RPB;

    // Hoist packed indices only (32 VGPRs), row-invariant.
    uint4 pk[ITS];
#pragma unroll
    for (int it = 0; it < ITS; ++it)
        pk[it] = *(const uint4*)(packed + (it * TPB + tid) * 4);

    uint4 tt[CHK];  // staged row, f16-packed (16 VGPRs)

    // Prologue: load + convert row0, write to lds[0].
    {
        const float4* s4 = (const float4*)(x + (size_t)row0 * IN_DIM);
#pragma unroll
        for (int c = 0; c < CHK; ++c) {
            float4 v0 = s4[(c * TPB + tid) * 2 + 0];
            float4 v1 = s4[(c * TPB + tid) * 2 + 1];
            tt[c].x = pack2(v0.x, v0.y); tt[c].y = pack2(v0.z, v0.w);
            tt[c].z = pack2(v1.x, v1.y); tt[c].w = pack2(v1.z, v1.w);
        }
#pragma unroll
        for (int c = 0; c < CHK; ++c)
            *(uint4*)((char*)lds[0] + (size_t)(c * TPB + tid) * 16) = tt[c];
    }

    for (int r = 0; r < RPB; ++r) {
        const int cur = r & 1;
        __syncthreads();  // lgkm drain: lds[cur] staged; prior reads of lds[cur^1] done

        const bool pf = (r + 1 < RPB);
        if (pf) {
            const float4* s4 = (const float4*)(x + (size_t)(row0 + r + 1) * IN_DIM);
#pragma unroll
            for (int c = 0; c < CHK; ++c) {
                float4 v0 = s4[(c * TPB + tid) * 2 + 0];
                float4 v1 = s4[(c * TPB + tid) * 2 + 1];
                tt[c].x = pack2(v0.x, v0.y); tt[c].y = pack2(v0.z, v0.w);
                tt[c].z = pack2(v1.x, v1.y); tt[c].w = pack2(v1.z, v1.w);
            }
        }
        __builtin_amdgcn_sched_barrier(0);  // pin prefetch load issue before compute

        const char* bufc = (const char*)lds[cur];
        float* outr = out + (size_t)(row0 + r) * IN_DIM;

#pragma unroll
        for (int it = 0; it < ITS; ++it) {
            const int j0 = (it * TPB + tid) * 4;
            const uint4 pi = pk[it];

            // cf streamed from L2; consumed only by the last FMAs.
            const h2x2 cA = coefh[j0 + 0];
            const h2x2 cB = coefh[j0 + 1];
            const h2x2 cC = coefh[j0 + 2];
            const h2x2 cD = coefh[j0 + 3];

            f32x4 o;
#define COL(P, CF, FLD)                                                             \
            {                                                                       \
                float a = __half2float(*(const __half*)(bufc + ((P) & 0xFFFFu)));   \
                float b = __half2float(*(const __half*)(bufc + ((P) >> 16)));       \
                float c0 = __low2float(CF.ab), c1 = __high2float(CF.ab);            \
                float c2 = __low2float(CF.cd), c3 = __high2float(CF.cd);            \
                o.FLD = fmaf(a, fmaf(c3, b, c1), fmaf(c2, b, c0));                  \
            }
            COL(pi.x, cA, x)
            COL(pi.y, cB, y)
            COL(pi.z, cC, z)
            COL(pi.w, cD, w)
#undef COL
            *(f32x4*)(outr + j0) = o;
        }

        if (pf) {
            char* dst = (char*)lds[cur ^ 1];
#pragma unroll
            for (int c = 0; c < CHK; ++c)
                *(uint4*)(dst + (size_t)(c * TPB + tid) * 16) = tt[c];
        }
    }
}

extern "C" void kernel_launch(void* const* d_in, const int* in_sizes, int n_in,
                              void* d_out, int out_size, void* d_ws, size_t ws_size,
                              hipStream_t stream) {
    const float* x = (const float*)d_in[0];
    const int* ia = (const int*)d_in[1];
    const int* ib = (const int*)d_in[2];
    const float* w = (const float*)d_in[3];
    float* out = (float*)d_out;

    // ws layout: [0, 128 KiB) coefh h2x2[OUT_DIM]; [128 KiB, 192 KiB) packed u32[OUT_DIM]
    h2x2* coefh = (h2x2*)d_ws;
    unsigned* packed = (unsigned*)((char*)d_ws + (size_t)OUT_DIM * sizeof(h2x2));

    prep_kernel<<<OUT_DIM / 256, 256, 0, stream>>>(w, ia, ib, coefh, packed);
    logic_kernel<<<NBLK, TPB, 0, stream>>>(x, packed, coefh, out);
}

// Round 10
// 63.225 us; speedup vs baseline: 2.4815x; 2.4815x over previous
//
#include <hip/hip_runtime.h>
#include <hip/hip_fp16.h>

#define IN_DIM  16384
#define OUT_DIM 16384
#define BATCH   2048
#define NBLK    512
#define RPB     (BATCH / NBLK)          // 4 rows per block
#define TPB     512
#define ITS     (OUT_DIM / (TPB * 4))   // 8 j-iterations (4 columns each)
#define CHK     (IN_DIM / (TPB * 8))    // 4 chunks of 8 floats per thread

typedef float f32x4 __attribute__((ext_vector_type(4)));

// Two half2's per output column: ab = (c0, c1), cd = (c2, c3). 8 bytes.
struct h2x2 { __half2 ab, cd; };

// OP_COEFFS from the reference, row-major [16][4]
__device__ __constant__ float OPC[16][4] = {
    {0.f, 0.f, 0.f, 0.f}, {0.f, 0.f, 0.f, 1.f}, {0.f, 1.f, 0.f, -1.f}, {0.f, 1.f, 0.f, 0.f},
    {0.f, 0.f, 1.f, -1.f}, {0.f, 0.f, 1.f, 0.f}, {0.f, 1.f, 1.f, -2.f}, {0.f, 1.f, 1.f, -1.f},
    {1.f, -1.f, -1.f, 1.f}, {1.f, -1.f, -1.f, 2.f}, {1.f, 0.f, -1.f, 0.f}, {1.f, 0.f, -1.f, 1.f},
    {1.f, -1.f, 0.f, 0.f}, {1.f, -1.f, 0.f, 1.f}, {1.f, 0.f, 0.f, -1.f}, {1.f, 0.f, 0.f, 0.f}};

// Prep: coef (f16x4) + packed f16-LDS byte offsets: (idx_a*2) | (idx_b*2)<<16.
__global__ __launch_bounds__(256) void prep_kernel(const float* __restrict__ w,
                                                   const int* __restrict__ ia,
                                                   const int* __restrict__ ib,
                                                   h2x2* __restrict__ coefh,
                                                   unsigned* __restrict__ packed) {
    int j = blockIdx.x * 256 + threadIdx.x;
    if (j >= OUT_DIM) return;

    const float4* wr = (const float4*)(w + (size_t)j * 16);
    float wv[16];
    float4 w0 = wr[0], w1 = wr[1], w2 = wr[2], w3 = wr[3];
    wv[0] = w0.x; wv[1] = w0.y; wv[2] = w0.z; wv[3] = w0.w;
    wv[4] = w1.x; wv[5] = w1.y; wv[6] = w1.z; wv[7] = w1.w;
    wv[8] = w2.x; wv[9] = w2.y; wv[10] = w2.z; wv[11] = w2.w;
    wv[12] = w3.x; wv[13] = w3.y; wv[14] = w3.z; wv[15] = w3.w;

    float m = wv[0];
#pragma unroll
    for (int k = 1; k < 16; ++k) m = fmaxf(m, wv[k]);
    float s = 0.f;
#pragma unroll
    for (int k = 0; k < 16; ++k) { wv[k] = expf(wv[k] - m); s += wv[k]; }
    float inv = 1.f / s;

    float c0 = 0.f, c1 = 0.f, c2 = 0.f, c3 = 0.f;
#pragma unroll
    for (int k = 0; k < 16; ++k) {
        float p = wv[k];
        c0 = fmaf(p, OPC[k][0], c0);
        c1 = fmaf(p, OPC[k][1], c1);
        c2 = fmaf(p, OPC[k][2], c2);
        c3 = fmaf(p, OPC[k][3], c3);
    }
    h2x2 c;
    c.ab = __floats2half2_rn(c0 * inv, c1 * inv);
    c.cd = __floats2half2_rn(c2 * inv, c3 * inv);
    coefh[j] = c;
    packed[j] = ((unsigned)ia[j] << 1) | ((unsigned)ib[j] << 17);
}

__device__ __forceinline__ unsigned pack2(float a, float b) {
    // single v_cvt_pkrtz_f16_f32 (round-toward-zero; err <= 2^-11, margin is 4.7x)
    return __builtin_bit_cast(unsigned, __builtin_amdgcn_cvt_pkrtz(a, b));
}

// f16 row double-buffer (2x32KiB = 64KiB LDS) -> 2 independent blocks/CU:
// barrier drains of one block overlap the other block's compute. pk hoisted
// (address critical path); cf STREAMED from L2 per iteration (consumed by the
// final FMAs, latency hides under ds_read). Stage regs f16-packed (16 VGPRs).
//
// __launch_bounds__(512, 2): empirically (R6/R7/R8) this gives a 128-VGPR cap;
// the ",4" variant capped at 64 and spilled everything (R8: 177us). Demand
// here is ~90 regs -> no spill, and actual VGPR<=128 keeps 2 blocks/CU.
__global__ __launch_bounds__(TPB, 2) void logic_kernel(const float* __restrict__ x,
                                                       const unsigned* __restrict__ packed,
                                                       const h2x2* __restrict__ coefh,
                                                       float* __restrict__ out) {
    __shared__ __half lds[2][IN_DIM];  // 64 KiB total -> 2 blocks/CU

    const int tid = threadIdx.x;
    const int row0 = blockIdx.x * RPB;

    // Hoist packed indices only (32 VGPRs), row-invariant.
    uint4 pk[ITS];
#pragma unroll
    for (int it = 0; it < ITS; ++it)
        pk[it] = *(const uint4*)(packed + (it * TPB + tid) * 4);

    uint4 tt[CHK];  // staged row, f16-packed (16 VGPRs)

    // Prologue: load + convert row0, write to lds[0].
    {
        const float4* s4 = (const float4*)(x + (size_t)row0 * IN_DIM);
#pragma unroll
        for (int c = 0; c < CHK; ++c) {
            float4 v0 = s4[(c * TPB + tid) * 2 + 0];
            float4 v1 = s4[(c * TPB + tid) * 2 + 1];
            tt[c].x = pack2(v0.x, v0.y); tt[c].y = pack2(v0.z, v0.w);
            tt[c].z = pack2(v1.x, v1.y); tt[c].w = pack2(v1.z, v1.w);
        }
#pragma unroll
        for (int c = 0; c < CHK; ++c)
            *(uint4*)((char*)lds[0] + (size_t)(c * TPB + tid) * 16) = tt[c];
    }

    for (int r = 0; r < RPB; ++r) {
        const int cur = r & 1;
        __syncthreads();  // lgkm drain: lds[cur] staged; prior reads of lds[cur^1] done

        const bool pf = (r + 1 < RPB);
        if (pf) {
            const float4* s4 = (const float4*)(x + (size_t)(row0 + r + 1) * IN_DIM);
#pragma unroll
            for (int c = 0; c < CHK; ++c) {
                float4 v0 = s4[(c * TPB + tid) * 2 + 0];
                float4 v1 = s4[(c * TPB + tid) * 2 + 1];
                tt[c].x = pack2(v0.x, v0.y); tt[c].y = pack2(v0.z, v0.w);
                tt[c].z = pack2(v1.x, v1.y); tt[c].w = pack2(v1.z, v1.w);
            }
        }
        __builtin_amdgcn_sched_barrier(0);  // pin prefetch load issue before compute

        const char* bufc = (const char*)lds[cur];
        float* outr = out + (size_t)(row0 + r) * IN_DIM;

#pragma unroll
        for (int it = 0; it < ITS; ++it) {
            const int j0 = (it * TPB + tid) * 4;
            const uint4 pi = pk[it];

            // cf streamed from L2; consumed only by the last FMAs.
            const h2x2 cA = coefh[j0 + 0];
            const h2x2 cB = coefh[j0 + 1];
            const h2x2 cC = coefh[j0 + 2];
            const h2x2 cD = coefh[j0 + 3];

            f32x4 o;
#define COL(P, CF, FLD)                                                             \
            {                                                                       \
                float a = __half2float(*(const __half*)(bufc + ((P) & 0xFFFFu)));   \
                float b = __half2float(*(const __half*)(bufc + ((P) >> 16)));       \
                float c0 = __low2float(CF.ab), c1 = __high2float(CF.ab);            \
                float c2 = __low2float(CF.cd), c3 = __high2float(CF.cd);            \
                o.FLD = fmaf(a, fmaf(c3, b, c1), fmaf(c2, b, c0));                  \
            }
            COL(pi.x, cA, x)
            COL(pi.y, cB, y)
            COL(pi.z, cC, z)
            COL(pi.w, cD, w)
#undef COL
            *(f32x4*)(outr + j0) = o;
        }

        if (pf) {
            char* dst = (char*)lds[cur ^ 1];
#pragma unroll
            for (int c = 0; c < CHK; ++c)
                *(uint4*)(dst + (size_t)(c * TPB + tid) * 16) = tt[c];
        }
    }
}

extern "C" void kernel_launch(void* const* d_in, const int* in_sizes, int n_in,
                              void* d_out, int out_size, void* d_ws, size_t ws_size,
                              hipStream_t stream) {
    const float* x = (const float*)d_in[0];
    const int* ia = (const int*)d_in[1];
    const int* ib = (const int*)d_in[2];
    const float* w = (const float*)d_in[3];
    float* out = (float*)d_out;

    // ws layout: [0, 128 KiB) coefh h2x2[OUT_DIM]; [128 KiB, 192 KiB) packed u32[OUT_DIM]
    h2x2* coefh = (h2x2*)d_ws;
    unsigned* packed = (unsigned*)((char*)d_ws + (size_t)OUT_DIM * sizeof(h2x2));

    prep_kernel<<<OUT_DIM / 256, 256, 0, stream>>>(w, ia, ib, coefh, packed);
    logic_kernel<<<NBLK, TPB, 0, stream>>>(x, packed, coefh, out);
}

// Round 11
// 58.683 us; speedup vs baseline: 2.6736x; 1.0774x over previous
//
#include <hip/hip_runtime.h>
#include <hip/hip_fp16.h>

#define IN_DIM  16384
#define OUT_DIM 16384
#define BATCH   2048
#define TPB     512
#define ITS     (OUT_DIM / (TPB * 4))   // 8 j-iterations (4 columns each)
#define CHK     (IN_DIM / (TPB * 8))    // 4 stage chunks of 8 floats per thread

typedef float f32x4 __attribute__((ext_vector_type(4)));

// Two half2's per output column: ab = (c0, c1), cd = (c2, c3). 8 bytes.
struct h2x2 { __half2 ab, cd; };

// OP_COEFFS from the reference, row-major [16][4]
__device__ __constant__ float OPC[16][4] = {
    {0.f, 0.f, 0.f, 0.f}, {0.f, 0.f, 0.f, 1.f}, {0.f, 1.f, 0.f, -1.f}, {0.f, 1.f, 0.f, 0.f},
    {0.f, 0.f, 1.f, -1.f}, {0.f, 0.f, 1.f, 0.f}, {0.f, 1.f, 1.f, -2.f}, {0.f, 1.f, 1.f, -1.f},
    {1.f, -1.f, -1.f, 1.f}, {1.f, -1.f, -1.f, 2.f}, {1.f, 0.f, -1.f, 0.f}, {1.f, 0.f, -1.f, 1.f},
    {1.f, -1.f, 0.f, 0.f}, {1.f, -1.f, 0.f, 1.f}, {1.f, 0.f, 0.f, -1.f}, {1.f, 0.f, 0.f, 0.f}};

// Prep: coef (f16x4) + packed f16-LDS byte offsets: (idx_a*2) | (idx_b*2)<<16.
__global__ __launch_bounds__(256) void prep_kernel(const float* __restrict__ w,
                                                   const int* __restrict__ ia,
                                                   const int* __restrict__ ib,
                                                   h2x2* __restrict__ coefh,
                                                   unsigned* __restrict__ packed) {
    int j = blockIdx.x * 256 + threadIdx.x;
    if (j >= OUT_DIM) return;

    const float4* wr = (const float4*)(w + (size_t)j * 16);
    float wv[16];
    float4 w0 = wr[0], w1 = wr[1], w2 = wr[2], w3 = wr[3];
    wv[0] = w0.x; wv[1] = w0.y; wv[2] = w0.z; wv[3] = w0.w;
    wv[4] = w1.x; wv[5] = w1.y; wv[6] = w1.z; wv[7] = w1.w;
    wv[8] = w2.x; wv[9] = w2.y; wv[10] = w2.z; wv[11] = w2.w;
    wv[12] = w3.x; wv[13] = w3.y; wv[14] = w3.z; wv[15] = w3.w;

    float m = wv[0];
#pragma unroll
    for (int k = 1; k < 16; ++k) m = fmaxf(m, wv[k]);
    float s = 0.f;
#pragma unroll
    for (int k = 0; k < 16; ++k) { wv[k] = expf(wv[k] - m); s += wv[k]; }
    float inv = 1.f / s;

    float c0 = 0.f, c1 = 0.f, c2 = 0.f, c3 = 0.f;
#pragma unroll
    for (int k = 0; k < 16; ++k) {
        float p = wv[k];
        c0 = fmaf(p, OPC[k][0], c0);
        c1 = fmaf(p, OPC[k][1], c1);
        c2 = fmaf(p, OPC[k][2], c2);
        c3 = fmaf(p, OPC[k][3], c3);
    }
    h2x2 c;
    c.ab = __floats2half2_rn(c0 * inv, c1 * inv);
    c.cd = __floats2half2_rn(c2 * inv, c3 * inv);
    coefh[j] = c;
    packed[j] = ((unsigned)ia[j] << 1) | ((unsigned)ib[j] << 17);
}

__device__ __forceinline__ unsigned pack2(float a, float b) {
    // single v_cvt_pkrtz_f16_f32 (round-toward-zero; err <= 2^-11, margin is 4.7x)
    return __builtin_bit_cast(unsigned, __builtin_amdgcn_cvt_pkrtz(a, b));
}

// Single-shot: one row per block, 2048 blocks, 32 KiB f16 LDS row buffer.
// No double-buffer, no hoisting: per-thread register demand ~50, so the
// (512,4) 64-VGPR cap holds WITHOUT spill -> 8 waves/SIMD -> 4 blocks/CU
// resident. Overlap comes from co-resident blocks in different phases
// (stage / gather / store) with no shared barrier — the HW scheduler
// pipelines them. R10's 2-block design measured only ~19% occupancy;
// this quadruples resident parallelism per CU.
__global__ __launch_bounds__(TPB, 4) void logic_kernel(const float* __restrict__ x,
                                                       const unsigned* __restrict__ packed,
                                                       const h2x2* __restrict__ coefh,
                                                       float* __restrict__ out) {
    __shared__ __half lds[IN_DIM];  // 32 KiB

    const int tid = threadIdx.x;
    const size_t row = blockIdx.x;

    // Stage: 8 float4 loads (issued together for MLP), pack f32->f16, ds_write.
    {
        const float4* s4 = (const float4*)(x + row * IN_DIM);
        uint4 tt[CHK];
#pragma unroll
        for (int c = 0; c < CHK; ++c) {
            float4 v0 = s4[(c * TPB + tid) * 2 + 0];
            float4 v1 = s4[(c * TPB + tid) * 2 + 1];
            tt[c].x = pack2(v0.x, v0.y); tt[c].y = pack2(v0.z, v0.w);
            tt[c].z = pack2(v1.x, v1.y); tt[c].w = pack2(v1.z, v1.w);
        }
#pragma unroll
        for (int c = 0; c < CHK; ++c)
            *(uint4*)((char*)lds + (size_t)(c * TPB + tid) * 16) = tt[c];
    }
    __syncthreads();

    const char* bufc = (const char*)lds;
    float* outr = out + row * IN_DIM;

#pragma unroll
    for (int it = 0; it < ITS; ++it) {
        const int j0 = (it * TPB + tid) * 4;
        const uint4 pi = *(const uint4*)(packed + j0);

        const h2x2 cA = coefh[j0 + 0];
        const h2x2 cB = coefh[j0 + 1];
        const h2x2 cC = coefh[j0 + 2];
        const h2x2 cD = coefh[j0 + 3];

        f32x4 o;
#define COL(P, CF, FLD)                                                             \
        {                                                                           \
            float a = __half2float(*(const __half*)(bufc + ((P) & 0xFFFFu)));       \
            float b = __half2float(*(const __half*)(bufc + ((P) >> 16)));           \
            float c0 = __low2float(CF.ab), c1 = __high2float(CF.ab);                \
            float c2 = __low2float(CF.cd), c3 = __high2float(CF.cd);                \
            o.FLD = fmaf(a, fmaf(c3, b, c1), fmaf(c2, b, c0));                      \
        }
        COL(pi.x, cA, x)
        COL(pi.y, cB, y)
        COL(pi.z, cC, z)
        COL(pi.w, cD, w)
#undef COL
        *(f32x4*)(outr + j0) = o;
    }
}

extern "C" void kernel_launch(void* const* d_in, const int* in_sizes, int n_in,
                              void* d_out, int out_size, void* d_ws, size_t ws_size,
                              hipStream_t stream) {
    const float* x = (const float*)d_in[0];
    const int* ia = (const int*)d_in[1];
    const int* ib = (const int*)d_in[2];
    const float* w = (const float*)d_in[3];
    float* out = (float*)d_out;

    // ws layout: [0, 128 KiB) coefh h2x2[OUT_DIM]; [128 KiB, 192 KiB) packed u32[OUT_DIM]
    h2x2* coefh = (h2x2*)d_ws;
    unsigned* packed = (unsigned*)((char*)d_ws + (size_t)OUT_DIM * sizeof(h2x2));

    prep_kernel<<<OUT_DIM / 256, 256, 0, stream>>>(w, ia, ib, coefh, packed);
    logic_kernel<<<BATCH, TPB, 0, stream>>>(x, packed, coefh, out);
}

// Round 12
// 55.745 us; speedup vs baseline: 2.8145x; 1.0527x over previous
//
#include <hip/hip_runtime.h>
#include <hip/hip_fp16.h>

#define IN_DIM  16384
#define OUT_DIM 16384
#define BATCH   2048
#define TPB     512
#define ITS     (OUT_DIM / (TPB * 4))   // 8 j-iterations (4 columns each)
#define CHK     (IN_DIM / (TPB * 8))    // 4 stage chunks of 8 floats per thread

typedef float f32x4 __attribute__((ext_vector_type(4)));

// Two half2's per output column: ab = (c0, c1), cd = (c2, c3). 8 bytes.
struct h2x2 { __half2 ab, cd; };

// OP_COEFFS from the reference, row-major [16][4]
__device__ __constant__ float OPC[16][4] = {
    {0.f, 0.f, 0.f, 0.f}, {0.f, 0.f, 0.f, 1.f}, {0.f, 1.f, 0.f, -1.f}, {0.f, 1.f, 0.f, 0.f},
    {0.f, 0.f, 1.f, -1.f}, {0.f, 0.f, 1.f, 0.f}, {0.f, 1.f, 1.f, -2.f}, {0.f, 1.f, 1.f, -1.f},
    {1.f, -1.f, -1.f, 1.f}, {1.f, -1.f, -1.f, 2.f}, {1.f, 0.f, -1.f, 0.f}, {1.f, 0.f, -1.f, 1.f},
    {1.f, -1.f, 0.f, 0.f}, {1.f, -1.f, 0.f, 1.f}, {1.f, 0.f, 0.f, -1.f}, {1.f, 0.f, 0.f, 0.f}};

// Prep: coef (f16x4) + packed f16-LDS byte offsets: (idx_a*2) | (idx_b*2)<<16.
__global__ __launch_bounds__(256) void prep_kernel(const float* __restrict__ w,
                                                   const int* __restrict__ ia,
                                                   const int* __restrict__ ib,
                                                   h2x2* __restrict__ coefh,
                                                   unsigned* __restrict__ packed) {
    int j = blockIdx.x * 256 + threadIdx.x;
    if (j >= OUT_DIM) return;

    const float4* wr = (const float4*)(w + (size_t)j * 16);
    float wv[16];
    float4 w0 = wr[0], w1 = wr[1], w2 = wr[2], w3 = wr[3];
    wv[0] = w0.x; wv[1] = w0.y; wv[2] = w0.z; wv[3] = w0.w;
    wv[4] = w1.x; wv[5] = w1.y; wv[6] = w1.z; wv[7] = w1.w;
    wv[8] = w2.x; wv[9] = w2.y; wv[10] = w2.z; wv[11] = w2.w;
    wv[12] = w3.x; wv[13] = w3.y; wv[14] = w3.z; wv[15] = w3.w;

    float m = wv[0];
#pragma unroll
    for (int k = 1; k < 16; ++k) m = fmaxf(m, wv[k]);
    float s = 0.f;
#pragma unroll
    for (int k = 0; k < 16; ++k) { wv[k] = expf(wv[k] - m); s += wv[k]; }
    float inv = 1.f / s;

    float c0 = 0.f, c1 = 0.f, c2 = 0.f, c3 = 0.f;
#pragma unroll
    for (int k = 0; k < 16; ++k) {
        float p = wv[k];
        c0 = fmaf(p, OPC[k][0], c0);
        c1 = fmaf(p, OPC[k][1], c1);
        c2 = fmaf(p, OPC[k][2], c2);
        c3 = fmaf(p, OPC[k][3], c3);
    }
    h2x2 c;
    c.ab = __floats2half2_rn(c0 * inv, c1 * inv);
    c.cd = __floats2half2_rn(c2 * inv, c3 * inv);
    coefh[j] = c;
    packed[j] = ((unsigned)ia[j] << 1) | ((unsigned)ib[j] << 17);
}

__device__ __forceinline__ unsigned pack2(float a, float b) {
    return __builtin_bit_cast(unsigned, __builtin_amdgcn_cvt_pkrtz(a, b));
}

// Single-shot (R11 structure: 1 row/block, 32 KiB f16 LDS, 4 blocks/CU) with
// a depth-1 software pipeline on the inner loop: pi/cf for iteration it+1 are
// issued before computing it, so the ~250cy L2 latency hides under the
// gather+FMA+store of the current iteration. +24 regs -> ~60, still under the
// (512,4) 64-VGPR cap. it=0 prefetch overlaps the stage barrier wait.
__global__ __launch_bounds__(TPB, 4) void logic_kernel(const float* __restrict__ x,
                                                       const unsigned* __restrict__ packed,
                                                       const h2x2* __restrict__ coefh,
                                                       float* __restrict__ out) {
    __shared__ __half lds[IN_DIM];  // 32 KiB

    const int tid = threadIdx.x;
    const size_t row = blockIdx.x;

    // Stage: 8 float4 loads, pack f32->f16, ds_write.
    {
        const float4* s4 = (const float4*)(x + row * IN_DIM);
        uint4 tt[CHK];
#pragma unroll
        for (int c = 0; c < CHK; ++c) {
            float4 v0 = s4[(c * TPB + tid) * 2 + 0];
            float4 v1 = s4[(c * TPB + tid) * 2 + 1];
            tt[c].x = pack2(v0.x, v0.y); tt[c].y = pack2(v0.z, v0.w);
            tt[c].z = pack2(v1.x, v1.y); tt[c].w = pack2(v1.z, v1.w);
        }
#pragma unroll
        for (int c = 0; c < CHK; ++c)
            *(uint4*)((char*)lds + (size_t)(c * TPB + tid) * 16) = tt[c];
    }

    // Prefetch iteration 0's pi/cf while waiting on the barrier.
    uint4 pi = *(const uint4*)(packed + tid * 4);
    h2x2 cA = coefh[tid * 4 + 0];
    h2x2 cB = coefh[tid * 4 + 1];
    h2x2 cC = coefh[tid * 4 + 2];
    h2x2 cD = coefh[tid * 4 + 3];

    __syncthreads();

    const char* bufc = (const char*)lds;
    float* outr = out + row * IN_DIM;

#pragma unroll
    for (int it = 0; it < ITS; ++it) {
        // Issue next iteration's loads first; they fly under this iteration's
        // gather + FMA + store.
        uint4 pin = pi;
        h2x2 nA = cA, nB = cB, nC = cC, nD = cD;
        if (it + 1 < ITS) {
            const int jn = ((it + 1) * TPB + tid) * 4;
            pin = *(const uint4*)(packed + jn);
            nA = coefh[jn + 0];
            nB = coefh[jn + 1];
            nC = coefh[jn + 2];
            nD = coefh[jn + 3];
        }
        __builtin_amdgcn_sched_barrier(0);  // keep prefetch issue ahead of compute

        const int j0 = (it * TPB + tid) * 4;
        f32x4 o;
#define COL(P, CF, FLD)                                                             \
        {                                                                           \
            float a = __half2float(*(const __half*)(bufc + ((P) & 0xFFFFu)));       \
            float b = __half2float(*(const __half*)(bufc + ((P) >> 16)));           \
            float c0 = __low2float(CF.ab), c1 = __high2float(CF.ab);                \
            float c2 = __low2float(CF.cd), c3 = __high2float(CF.cd);                \
            o.FLD = fmaf(a, fmaf(c3, b, c1), fmaf(c2, b, c0));                      \
        }
        COL(pi.x, cA, x)
        COL(pi.y, cB, y)
        COL(pi.z, cC, z)
        COL(pi.w, cD, w)
#undef COL
        *(f32x4*)(outr + j0) = o;

        pi = pin; cA = nA; cB = nB; cC = nC; cD = nD;
    }
}

extern "C" void kernel_launch(void* const* d_in, const int* in_sizes, int n_in,
                              void* d_out, int out_size, void* d_ws, size_t ws_size,
                              hipStream_t stream) {
    const float* x = (const float*)d_in[0];
    const int* ia = (const int*)d_in[1];
    const int* ib = (const int*)d_in[2];
    const float* w = (const float*)d_in[3];
    float* out = (float*)d_out;

    // ws layout: [0, 128 KiB) coefh h2x2[OUT_DIM]; [128 KiB, 192 KiB) packed u32[OUT_DIM]
    h2x2* coefh = (h2x2*)d_ws;
    unsigned* packed = (unsigned*)((char*)d_ws + (size_t)OUT_DIM * sizeof(h2x2));

    prep_kernel<<<OUT_DIM / 256, 256, 0, stream>>>(w, ia, ib, coefh, packed);
    logic_kernel<<<BATCH, TPB, 0, stream>>>(x, packed, coefh, out);
}